// Round 6
// baseline (239.468 us; speedup 1.0000x reference)
//
#include <hip/hip_runtime.h>

// Llama attention block, gfx950. Round 6:
//  - GEMMs: BK=64 (16 MFMA per barrier-pair, 24 KB LDS, 8-chunk XOR swizzle)
//  - attention: BARRIER-FREE kv loop. K and Vt global layouts coincide with
//    the MFMA B-fragment layouts, so K/V fragments load straight from global
//    (coalesced dwordx4, L2-resident); only Ps round-trips through LDS
//    (wave-private). Max-free softmax in exp2 domain (Q pre-scaled).
//  - prep: one vectorized dispatch (x->bf16 + 4 weight transposes).
// Shapes: B=1, S=2048, D=2048, H=32, KVH=8, HD=64.

#define NH  32
#define NKV 8

typedef __attribute__((ext_vector_type(8))) __bf16 bf16x8;
typedef __attribute__((ext_vector_type(4))) __bf16 bf16x4;
typedef __attribute__((ext_vector_type(4))) float  f32x4;

#define SCALE_LOG2 0.18033688011112042f   // (1/sqrt(64)) * log2(e)
#define L2_10K_32  0.41524101186098665f   // log2(10000)/32

__device__ __forceinline__ void glds16(const __bf16* g, __bf16* l) {
  __builtin_amdgcn_global_load_lds(
      (const __attribute__((address_space(1))) unsigned int*)g,
      (__attribute__((address_space(3))) unsigned int*)l, 16, 0, 0);
}

// swap lanes lid <-> lid^1 (quad_perm [1,0,3,2])
__device__ __forceinline__ float pair_swap(float v) {
  int t = __builtin_amdgcn_mov_dpp(__builtin_bit_cast(int, v), 0xB1, 0xf, 0xf, true);
  return __builtin_bit_cast(float, t);
}

__device__ __forceinline__ unsigned pack_bf16(float lo, float hi) {
  union { __bf16 b[2]; unsigned u; } r;
  r.b[0] = (__bf16)lo; r.b[1] = (__bf16)hi;
  return r.u;
}

// ---------------------------------------------------------------- prep
// blockIdx.x: [0,64) Wq | [64,80) Wk | [80,96) Wv | [96,160) Wo -> N x 2048
// bf16 transposed; [160,224) x fp32 -> bf16 convert.
__global__ __launch_bounds__(256) void k_prep(
    const float* __restrict__ hx, const float* __restrict__ Wq,
    const float* __restrict__ Wk, const float* __restrict__ Wv,
    const float* __restrict__ Wo, __bf16* __restrict__ Xb,
    __bf16* __restrict__ Wqkvt, __bf16* __restrict__ Wot) {
  __shared__ float t[32 * 36];
  const int nt = blockIdx.x, k0 = blockIdx.y * 32;
  const int tid = threadIdx.x;
  const int r = tid >> 3, c4 = (tid & 7) * 4;
  if (nt >= 160) {
    int c0 = (nt - 160) * 32;
    float4 v = *(const float4*)(hx + (size_t)(k0 + r) * 2048 + c0 + c4);
    bf16x4 o;
    o[0] = (__bf16)v.x; o[1] = (__bf16)v.y; o[2] = (__bf16)v.z; o[3] = (__bf16)v.w;
    *(bf16x4*)(Xb + (size_t)(k0 + r) * 2048 + c0 + c4) = o;
    return;
  }
  const float* W; int ldW, n0; __bf16* dst;
  if (nt < 64)      { W = Wq; ldW = 2048; dst = Wqkvt;                       n0 = nt * 32; }
  else if (nt < 80) { W = Wk; ldW = 512;  dst = Wqkvt + (size_t)2048 * 2048; n0 = (nt - 64) * 32; }
  else if (nt < 96) { W = Wv; ldW = 512;  dst = Wqkvt + (size_t)2560 * 2048; n0 = (nt - 80) * 32; }
  else              { W = Wo; ldW = 2048; dst = Wot;                         n0 = (nt - 96) * 32; }
  float4 v = *(const float4*)(W + (size_t)(k0 + r) * ldW + n0 + c4);
  *(float4*)(t + r * 36 + ((((c4 >> 2) ^ r) & 7) << 2)) = v;
  __syncthreads();
  bf16x4 o;
#pragma unroll
  for (int j = 0; j < 4; j++) {
    int kk = c4 + j;
    o[j] = (__bf16)t[kk * 36 + ((((r >> 2) ^ kk) & 7) << 2) + (r & 3)];
  }
  *(bf16x4*)(dst + (size_t)(n0 + r) * 2048 + k0 + c4) = o;
}

// V (seq x 512 bf16) -> Vt (512 x seq bf16)
__global__ void k_vtrans_b(const __bf16* __restrict__ V, __bf16* __restrict__ Vt) {
  __shared__ __bf16 t[32][33];
  int c0 = blockIdx.x * 32, s0 = blockIdx.y * 32;
  int tx = threadIdx.x, ty = threadIdx.y;
#pragma unroll
  for (int j = 0; j < 4; j++)
    t[ty + j * 8][tx] = V[(size_t)(s0 + ty + j * 8) * 512 + c0 + tx];
  __syncthreads();
#pragma unroll
  for (int j = 0; j < 4; j++)
    Vt[(size_t)(c0 + ty + j * 8) * 2048 + s0 + tx] = t[tx][ty + j * 8];
}

// ---------------------------------------------------------------- QKV GEMM
// 64x128 tile, BK=64, 4 waves (wave tile 32x64). RoPE epilogue -> bf16.
__global__ __launch_bounds__(256) void k_gemm_qkv(
    const __bf16* __restrict__ A, const __bf16* __restrict__ Bt,
    __bf16* __restrict__ Qb, __bf16* __restrict__ Kb, __bf16* __restrict__ Vb) {
  const int K = 2048;
  __shared__ __bf16 As[64][64];
  __shared__ __bf16 Bs[128][64];
  const int tid = threadIdx.x;
  const int m0 = blockIdx.x * 64, n0 = blockIdx.y * 128;
  const int w = tid >> 6, lane = tid & 63, quad = lane >> 4, lid = lane & 15;
  const int wm = (w & 1) * 32, wn = (w >> 1) * 64;
  const int r0 = tid >> 3;                         // staging row (+32 per 256)
  const int cg0 = (((tid & 7) ^ (r0 & 7)) * 8);    // swizzled global chunk
  const __bf16* Ag = A + (size_t)(m0 + r0) * K + cg0;
  const __bf16* Bg = Bt + (size_t)(n0 + r0) * K + cg0;
  __bf16* Asl = &As[0][0] + tid * 8;
  __bf16* Bsl = &Bs[0][0] + tid * 8;
  const int cl = ((quad ^ (lid & 7)) * 8);         // frag col, chunk=quad
  f32x4 acc[2][4] = {};
  for (int k0 = 0; k0 < K; k0 += 64) {
    __syncthreads();
    glds16(Ag + k0, Asl);
    glds16(Ag + (size_t)32 * K + k0, Asl + 2048);
    glds16(Bg + k0, Bsl);
    glds16(Bg + (size_t)32 * K + k0, Bsl + 2048);
    glds16(Bg + (size_t)64 * K + k0, Bsl + 4096);
    glds16(Bg + (size_t)96 * K + k0, Bsl + 6144);
    __syncthreads();
    bf16x8 a[2][2], b[4][2];
#pragma unroll
    for (int mt = 0; mt < 2; mt++) {
      a[mt][0] = *(const bf16x8*)(&As[wm + mt * 16 + lid][cl]);
      a[mt][1] = *(const bf16x8*)(&As[wm + mt * 16 + lid][cl ^ 32]);
    }
#pragma unroll
    for (int nt = 0; nt < 4; nt++) {
      b[nt][0] = *(const bf16x8*)(&Bs[wn + nt * 16 + lid][cl]);
      b[nt][1] = *(const bf16x8*)(&Bs[wn + nt * 16 + lid][cl ^ 32]);
    }
#pragma unroll
    for (int mt = 0; mt < 2; mt++)
#pragma unroll
      for (int nt = 0; nt < 4; nt++) {
        acc[mt][nt] = __builtin_amdgcn_mfma_f32_16x16x32_bf16(
            a[mt][0], b[nt][0], acc[mt][nt], 0, 0, 0);
        acc[mt][nt] = __builtin_amdgcn_mfma_f32_16x16x32_bf16(
            a[mt][1], b[nt][1], acc[mt][nt], 0, 0, 0);
      }
  }
  if (n0 >= 2560) {
#pragma unroll
    for (int mt = 0; mt < 2; mt++)
#pragma unroll
      for (int nt = 0; nt < 4; nt++)
#pragma unroll
        for (int i = 0; i < 4; i++) {
          int mm = m0 + wm + mt * 16 + quad * 4 + i;
          int nn = n0 + wn + nt * 16 + lid - 2560;
          Vb[(size_t)mm * 512 + nn] = (__bf16)acc[mt][nt][i];
        }
  } else {
    const bool isQ = (n0 < 2048);
    const float scale = isQ ? SCALE_LOG2 : 1.0f;
    __bf16* dst = isQ ? Qb : Kb;
    const int ldd = isQ ? 2048 : 512;
    const int noff = isQ ? 0 : 2048;
    const bool odd = lid & 1;
#pragma unroll
    for (int nt = 0; nt < 4; nt++) {
      int nn = n0 + wn + nt * 16 + lid;
      int fi = (nn & 63) >> 1;
      float inv = __builtin_amdgcn_exp2f(-(float)fi * L2_10K_32);
#pragma unroll
      for (int mt = 0; mt < 2; mt++)
#pragma unroll
        for (int i = 0; i < 4; i++) {
          int mm = m0 + wm + mt * 16 + quad * 4 + i;
          float ang = (float)mm * inv;
          float sn, cs;
          __sincosf(ang, &sn, &cs);
          float v = acc[mt][nt][i];
          float p = __shfl_xor(v, 1);
          float o = v * cs + (odd ? p : -p) * sn;
          dst[(size_t)mm * ldd + nn - noff] = (__bf16)(o * scale);
        }
    }
  }
}

// ---------------------------------------------------------------- out GEMM
// 64x128 tile, BK=64, full-K, fp32 C.
__global__ __launch_bounds__(256) void k_gemm_out(
    const __bf16* __restrict__ A, const __bf16* __restrict__ Bt,
    float* __restrict__ C) {
  const int K = 2048, N = 2048;
  __shared__ __bf16 As[64][64];
  __shared__ __bf16 Bs[128][64];
  const int tid = threadIdx.x;
  const int m0 = blockIdx.x * 64, n0 = blockIdx.y * 128;
  const int w = tid >> 6, lane = tid & 63, quad = lane >> 4, lid = lane & 15;
  const int wm = (w & 1) * 32, wn = (w >> 1) * 64;
  const int r0 = tid >> 3;
  const int cg0 = (((tid & 7) ^ (r0 & 7)) * 8);
  const __bf16* Ag = A + (size_t)(m0 + r0) * K + cg0;
  const __bf16* Bg = Bt + (size_t)(n0 + r0) * K + cg0;
  __bf16* Asl = &As[0][0] + tid * 8;
  __bf16* Bsl = &Bs[0][0] + tid * 8;
  const int cl = ((quad ^ (lid & 7)) * 8);
  f32x4 acc[2][4] = {};
  for (int k0 = 0; k0 < K; k0 += 64) {
    __syncthreads();
    glds16(Ag + k0, Asl);
    glds16(Ag + (size_t)32 * K + k0, Asl + 2048);
    glds16(Bg + k0, Bsl);
    glds16(Bg + (size_t)32 * K + k0, Bsl + 2048);
    glds16(Bg + (size_t)64 * K + k0, Bsl + 4096);
    glds16(Bg + (size_t)96 * K + k0, Bsl + 6144);
    __syncthreads();
    bf16x8 a[2][2], b[4][2];
#pragma unroll
    for (int mt = 0; mt < 2; mt++) {
      a[mt][0] = *(const bf16x8*)(&As[wm + mt * 16 + lid][cl]);
      a[mt][1] = *(const bf16x8*)(&As[wm + mt * 16 + lid][cl ^ 32]);
    }
#pragma unroll
    for (int nt = 0; nt < 4; nt++) {
      b[nt][0] = *(const bf16x8*)(&Bs[wn + nt * 16 + lid][cl]);
      b[nt][1] = *(const bf16x8*)(&Bs[wn + nt * 16 + lid][cl ^ 32]);
    }
#pragma unroll
    for (int mt = 0; mt < 2; mt++)
#pragma unroll
      for (int nt = 0; nt < 4; nt++) {
        acc[mt][nt] = __builtin_amdgcn_mfma_f32_16x16x32_bf16(
            a[mt][0], b[nt][0], acc[mt][nt], 0, 0, 0);
        acc[mt][nt] = __builtin_amdgcn_mfma_f32_16x16x32_bf16(
            a[mt][1], b[nt][1], acc[mt][nt], 0, 0, 0);
      }
  }
#pragma unroll
  for (int mt = 0; mt < 2; mt++)
#pragma unroll
    for (int nt = 0; nt < 4; nt++)
#pragma unroll
      for (int i = 0; i < 4; i++) {
        int mm = m0 + wm + mt * 16 + quad * 4 + i;
        int nn = n0 + wn + nt * 16 + lid;
        C[(size_t)mm * N + nn] = acc[mt][nt][i];
      }
}

// ---------------------------------------------------------------- attention
// Block = (head, 64-q tile), 4 waves: q-half qh=w&1, kv-half kh=w>>1.
// K/V MFMA B-fragments loaded DIRECTLY from global (layouts coincide);
// no __syncthreads in the kv loop. Max-free softmax, exp2 domain.
__global__ __launch_bounds__(256, 4) void k_attn(
    const __bf16* __restrict__ Q, const __bf16* __restrict__ Kc,
    const __bf16* __restrict__ Vt, __bf16* __restrict__ Oc) {
  __shared__ __bf16 Ps[4][32][40];   // per-wave P (32q x 32kv, pad 8)
  __shared__ float OL[2][32][68];    // kv-half merge buffer
  __shared__ float Lsh[64];
  const int h = blockIdx.x;
  const int qt = 31 - blockIdx.y;    // longest blocks first
  const int q0 = qt * 64;
  const int kvh = h >> 2;
  const int tid = threadIdx.x;
  const int w = tid >> 6, lane = tid & 63, quad = lane >> 4, lid = lane & 15;
  const int qh = w & 1, kh = w >> 1;

  // Q A-fragments from global
  bf16x8 aq[2][2];
#pragma unroll
  for (int mt = 0; mt < 2; mt++)
#pragma unroll
    for (int ks = 0; ks < 2; ks++)
      aq[mt][ks] = *(const bf16x8*)(
          Q + (size_t)(q0 + qh * 32 + mt * 16 + lid) * 2048 + h * 64 +
          ks * 32 + quad * 8);

  bf16x8 bone;
#pragma unroll
  for (int j = 0; j < 8; j++) bone[j] = (lid == 0) ? (__bf16)1.0f : (__bf16)0.0f;

  // fragment base pointers (lane-dependent part folded in)
  const __bf16* Kfr = Kc + (size_t)(kh * 32 + lid) * 512 + kvh * 64 + quad * 8;
  const __bf16* Vfr = Vt + (size_t)(kvh * 64 + lid) * 2048 + kh * 32 + quad * 8;

  f32x4 Oacc[2][4] = {};
  f32x4 Lacc[2] = {};

  for (int kt = 0; kt <= qt; kt++) {
    const int kv0 = kt * 64;
    // K fragments: B[k=hd][n=kv] == K global rows (coalesced dwordx4)
    bf16x8 kf[2][2];
#pragma unroll
    for (int nt = 0; nt < 2; nt++)
#pragma unroll
      for (int ch = 0; ch < 2; ch++)
        kf[nt][ch] = *(const bf16x8*)(Kfr + (size_t)(kv0 + nt * 16) * 512 + ch * 32);
    // V fragments: B[k=kv][n=hd] == Vt global rows
    bf16x8 vf[4];
#pragma unroll
    for (int nt = 0; nt < 4; nt++)
      vf[nt] = *(const bf16x8*)(Vfr + (size_t)nt * 16 * 2048 + kv0);

    // S = Q K^T (exp2 domain via Q pre-scale)
    f32x4 Sc[2][2] = {};
#pragma unroll
    for (int nt = 0; nt < 2; nt++)
#pragma unroll
      for (int mt = 0; mt < 2; mt++) {
        Sc[mt][nt] = __builtin_amdgcn_mfma_f32_16x16x32_bf16(
            aq[mt][0], kf[nt][0], Sc[mt][nt], 0, 0, 0);
        Sc[mt][nt] = __builtin_amdgcn_mfma_f32_16x16x32_bf16(
            aq[mt][1], kf[nt][1], Sc[mt][nt], 0, 0, 0);
      }
    if (kt == qt) {                  // causal mask on diagonal tile
#pragma unroll
      for (int mt = 0; mt < 2; mt++)
#pragma unroll
        for (int nt = 0; nt < 2; nt++)
#pragma unroll
          for (int i = 0; i < 4; i++) {
            int kvg = kv0 + kh * 32 + nt * 16 + lid;
            int qrg = q0 + qh * 32 + mt * 16 + quad * 4 + i;
            if (kvg > qrg) Sc[mt][nt][i] = -1e30f;
          }
    }

    // P = exp2(S), pair-pack -> Ps (wave-private, no barrier)
#pragma unroll
    for (int mt = 0; mt < 2; mt++)
#pragma unroll
      for (int i = 0; i < 4; i++) {
        float pA = __builtin_amdgcn_exp2f(Sc[mt][0][i]);
        float pB = __builtin_amdgcn_exp2f(Sc[mt][1][i]);
        float send = (lid & 1) ? pA : pB;
        float recv = pair_swap(send);
        float lo = (lid & 1) ? recv : pA;
        float hi = (lid & 1) ? pB : recv;
        int row = mt * 16 + quad * 4 + i;
        int col = (lid & 1) ? (lid + 15) : lid;
        *(unsigned*)(&Ps[w][row][col]) = pack_bf16(lo, hi);
      }

    // O += P V ; L += P @ ones
    bf16x8 ap[2];
#pragma unroll
    for (int mt = 0; mt < 2; mt++)
      ap[mt] = *(const bf16x8*)(&Ps[w][mt * 16 + lid][quad * 8]);
#pragma unroll
    for (int mt = 0; mt < 2; mt++)
      Lacc[mt] = __builtin_amdgcn_mfma_f32_16x16x32_bf16(ap[mt], bone, Lacc[mt], 0, 0, 0);
#pragma unroll
    for (int nt = 0; nt < 4; nt++)
#pragma unroll
      for (int mt = 0; mt < 2; mt++)
        Oacc[mt][nt] = __builtin_amdgcn_mfma_f32_16x16x32_bf16(
            ap[mt], vf[nt], Oacc[mt][nt], 0, 0, 0);
  }

  // merge kv-halves (the only barrier in the kernel)
  if (kh == 1) {
#pragma unroll
    for (int mt = 0; mt < 2; mt++)
#pragma unroll
      for (int nt = 0; nt < 4; nt++)
#pragma unroll
        for (int i = 0; i < 4; i++)
          OL[qh][mt * 16 + quad * 4 + i][nt * 16 + lid] = Oacc[mt][nt][i];
    if (lid == 0)
#pragma unroll
      for (int mt = 0; mt < 2; mt++)
#pragma unroll
        for (int i = 0; i < 4; i++)
          Lsh[qh * 32 + mt * 16 + quad * 4 + i] = Lacc[mt][i];
  }
  __syncthreads();
  if (kh == 0) {
#pragma unroll
    for (int mt = 0; mt < 2; mt++)
#pragma unroll
      for (int i = 0; i < 4; i++) {
        int row = mt * 16 + quad * 4 + i;
        float lsum = __shfl(Lacc[mt][i], lane & 48) + Lsh[qh * 32 + row];
        float rs = 1.0f / lsum;
#pragma unroll
        for (int nt = 0; nt < 4; nt++) {
          float o = Oacc[mt][nt][i] + OL[qh][row][nt * 16 + lid];
          Oc[(size_t)(q0 + qh * 32 + row) * 2048 + h * 64 + nt * 16 + lid] =
              (__bf16)(o * rs);
        }
      }
  }
}

// ---------------------------------------------------------------- launch
extern "C" void kernel_launch(void* const* d_in, const int* in_sizes, int n_in,
                              void* d_out, int out_size, void* d_ws, size_t ws_size,
                              hipStream_t stream) {
  const float* hx = (const float*)d_in[0];
  const float* Wq = (const float*)d_in[1];
  const float* Wk = (const float*)d_in[2];
  const float* Wv = (const float*)d_in[3];
  const float* Wo = (const float*)d_in[4];
  float* out = (float*)d_out;

  char* ws = (char*)d_ws;
  size_t off = 0;
  auto alloc = [&](size_t bytes) -> void* {
    void* p = ws + off;
    off += (bytes + 255) & ~(size_t)255;
    return p;
  };
  __bf16* Xb    = (__bf16*)alloc((size_t)2048 * 2048 * 2);
  __bf16* Wqkvt = (__bf16*)alloc((size_t)3072 * 2048 * 2);
  __bf16* Wot   = (__bf16*)alloc((size_t)2048 * 2048 * 2);
  __bf16* Qb    = (__bf16*)alloc((size_t)2048 * 2048 * 2);
  __bf16* Kb    = (__bf16*)alloc((size_t)2048 * 512 * 2);
  __bf16* Vb    = (__bf16*)alloc((size_t)2048 * 512 * 2);
  __bf16* Vtg   = (__bf16*)alloc((size_t)512 * 2048 * 2);
  __bf16* AOb   = (__bf16*)alloc((size_t)2048 * 2048 * 2);

  // 1. prep: x->bf16 + weight transposes
  k_prep<<<dim3(224, 64), 256, 0, stream>>>(hx, Wq, Wk, Wv, Wo, Xb, Wqkvt, Wot);
  // 2. fused QKV GEMM (BK=64) with RoPE epilogue
  k_gemm_qkv<<<dim3(32, 24), 256, 0, stream>>>(Xb, Wqkvt, Qb, Kb, Vb);
  // 3. V transpose
  k_vtrans_b<<<dim3(16, 64), dim3(32, 8), 0, stream>>>(Vb, Vtg);
  // 4. causal GQA flash attention (barrier-free kv loop)
  k_attn<<<dim3(NH, 32), 256, 0, stream>>>(Qb, Kb, Vtg, AOb);
  // 5. out proj (BK=64) -> fp32 d_out
  k_gemm_out<<<dim3(32, 16), 256, 0, stream>>>(AOb, Wot, out);
}

// Round 7
// 198.311 us; speedup vs baseline: 1.2075x; 1.2075x over previous
//
#include <hip/hip_runtime.h>

// Llama attention block, gfx950. Round 7:
//  - attention: R5 structure (kv-split waves, max-free exp2 softmax, LDS-
//    staged K/V shared by all 4 waves) + R3's double-buffered glds prefetch
//    (stage kt+1 before computing kt; ONE barrier/iter whose drain overlaps
//    compute). 42 KB LDS; epilogue merge aliases dead K/V buffers.
//  - GEMMs: BK=64 (kept from R6), prep/vtrans unchanged.
// Shapes: B=1, S=2048, D=2048, H=32, KVH=8, HD=64.

#define NH  32
#define NKV 8

typedef __attribute__((ext_vector_type(8))) __bf16 bf16x8;
typedef __attribute__((ext_vector_type(4))) __bf16 bf16x4;
typedef __attribute__((ext_vector_type(4))) float  f32x4;

#define SCALE_LOG2 0.18033688011112042f   // (1/sqrt(64)) * log2(e)
#define L2_10K_32  0.41524101186098665f   // log2(10000)/32

__device__ __forceinline__ void glds16(const __bf16* g, __bf16* l) {
  __builtin_amdgcn_global_load_lds(
      (const __attribute__((address_space(1))) unsigned int*)g,
      (__attribute__((address_space(3))) unsigned int*)l, 16, 0, 0);
}

// swap lanes lid <-> lid^1 (quad_perm [1,0,3,2])
__device__ __forceinline__ float pair_swap(float v) {
  int t = __builtin_amdgcn_mov_dpp(__builtin_bit_cast(int, v), 0xB1, 0xf, 0xf, true);
  return __builtin_bit_cast(float, t);
}

__device__ __forceinline__ unsigned pack_bf16(float lo, float hi) {
  union { __bf16 b[2]; unsigned u; } r;
  r.b[0] = (__bf16)lo; r.b[1] = (__bf16)hi;
  return r.u;
}

// ---------------------------------------------------------------- prep
__global__ __launch_bounds__(256) void k_prep(
    const float* __restrict__ hx, const float* __restrict__ Wq,
    const float* __restrict__ Wk, const float* __restrict__ Wv,
    const float* __restrict__ Wo, __bf16* __restrict__ Xb,
    __bf16* __restrict__ Wqkvt, __bf16* __restrict__ Wot) {
  __shared__ float t[32 * 36];
  const int nt = blockIdx.x, k0 = blockIdx.y * 32;
  const int tid = threadIdx.x;
  const int r = tid >> 3, c4 = (tid & 7) * 4;
  if (nt >= 160) {
    int c0 = (nt - 160) * 32;
    float4 v = *(const float4*)(hx + (size_t)(k0 + r) * 2048 + c0 + c4);
    bf16x4 o;
    o[0] = (__bf16)v.x; o[1] = (__bf16)v.y; o[2] = (__bf16)v.z; o[3] = (__bf16)v.w;
    *(bf16x4*)(Xb + (size_t)(k0 + r) * 2048 + c0 + c4) = o;
    return;
  }
  const float* W; int ldW, n0; __bf16* dst;
  if (nt < 64)      { W = Wq; ldW = 2048; dst = Wqkvt;                       n0 = nt * 32; }
  else if (nt < 80) { W = Wk; ldW = 512;  dst = Wqkvt + (size_t)2048 * 2048; n0 = (nt - 64) * 32; }
  else if (nt < 96) { W = Wv; ldW = 512;  dst = Wqkvt + (size_t)2560 * 2048; n0 = (nt - 80) * 32; }
  else              { W = Wo; ldW = 2048; dst = Wot;                         n0 = (nt - 96) * 32; }
  float4 v = *(const float4*)(W + (size_t)(k0 + r) * ldW + n0 + c4);
  *(float4*)(t + r * 36 + ((((c4 >> 2) ^ r) & 7) << 2)) = v;
  __syncthreads();
  bf16x4 o;
#pragma unroll
  for (int j = 0; j < 4; j++) {
    int kk = c4 + j;
    o[j] = (__bf16)t[kk * 36 + ((((r >> 2) ^ kk) & 7) << 2) + (r & 3)];
  }
  *(bf16x4*)(dst + (size_t)(n0 + r) * 2048 + k0 + c4) = o;
}

// V (seq x 512 bf16) -> Vt (512 x seq bf16)
__global__ void k_vtrans_b(const __bf16* __restrict__ V, __bf16* __restrict__ Vt) {
  __shared__ __bf16 t[32][33];
  int c0 = blockIdx.x * 32, s0 = blockIdx.y * 32;
  int tx = threadIdx.x, ty = threadIdx.y;
#pragma unroll
  for (int j = 0; j < 4; j++)
    t[ty + j * 8][tx] = V[(size_t)(s0 + ty + j * 8) * 512 + c0 + tx];
  __syncthreads();
#pragma unroll
  for (int j = 0; j < 4; j++)
    Vt[(size_t)(c0 + ty + j * 8) * 2048 + s0 + tx] = t[tx][ty + j * 8];
}

// ---------------------------------------------------------------- QKV GEMM
// 64x128 tile, BK=64, 4 waves (wave tile 32x64). RoPE epilogue -> bf16.
__global__ __launch_bounds__(256) void k_gemm_qkv(
    const __bf16* __restrict__ A, const __bf16* __restrict__ Bt,
    __bf16* __restrict__ Qb, __bf16* __restrict__ Kb, __bf16* __restrict__ Vb) {
  const int K = 2048;
  __shared__ __bf16 As[64][64];
  __shared__ __bf16 Bs[128][64];
  const int tid = threadIdx.x;
  const int m0 = blockIdx.x * 64, n0 = blockIdx.y * 128;
  const int w = tid >> 6, lane = tid & 63, quad = lane >> 4, lid = lane & 15;
  const int wm = (w & 1) * 32, wn = (w >> 1) * 64;
  const int r0 = tid >> 3;
  const int cg0 = (((tid & 7) ^ (r0 & 7)) * 8);
  const __bf16* Ag = A + (size_t)(m0 + r0) * K + cg0;
  const __bf16* Bg = Bt + (size_t)(n0 + r0) * K + cg0;
  __bf16* Asl = &As[0][0] + tid * 8;
  __bf16* Bsl = &Bs[0][0] + tid * 8;
  const int cl = ((quad ^ (lid & 7)) * 8);
  f32x4 acc[2][4] = {};
  for (int k0 = 0; k0 < K; k0 += 64) {
    __syncthreads();
    glds16(Ag + k0, Asl);
    glds16(Ag + (size_t)32 * K + k0, Asl + 2048);
    glds16(Bg + k0, Bsl);
    glds16(Bg + (size_t)32 * K + k0, Bsl + 2048);
    glds16(Bg + (size_t)64 * K + k0, Bsl + 4096);
    glds16(Bg + (size_t)96 * K + k0, Bsl + 6144);
    __syncthreads();
    bf16x8 a[2][2], b[4][2];
#pragma unroll
    for (int mt = 0; mt < 2; mt++) {
      a[mt][0] = *(const bf16x8*)(&As[wm + mt * 16 + lid][cl]);
      a[mt][1] = *(const bf16x8*)(&As[wm + mt * 16 + lid][cl ^ 32]);
    }
#pragma unroll
    for (int nt = 0; nt < 4; nt++) {
      b[nt][0] = *(const bf16x8*)(&Bs[wn + nt * 16 + lid][cl]);
      b[nt][1] = *(const bf16x8*)(&Bs[wn + nt * 16 + lid][cl ^ 32]);
    }
#pragma unroll
    for (int mt = 0; mt < 2; mt++)
#pragma unroll
      for (int nt = 0; nt < 4; nt++) {
        acc[mt][nt] = __builtin_amdgcn_mfma_f32_16x16x32_bf16(
            a[mt][0], b[nt][0], acc[mt][nt], 0, 0, 0);
        acc[mt][nt] = __builtin_amdgcn_mfma_f32_16x16x32_bf16(
            a[mt][1], b[nt][1], acc[mt][nt], 0, 0, 0);
      }
  }
  if (n0 >= 2560) {
#pragma unroll
    for (int mt = 0; mt < 2; mt++)
#pragma unroll
      for (int nt = 0; nt < 4; nt++)
#pragma unroll
        for (int i = 0; i < 4; i++) {
          int mm = m0 + wm + mt * 16 + quad * 4 + i;
          int nn = n0 + wn + nt * 16 + lid - 2560;
          Vb[(size_t)mm * 512 + nn] = (__bf16)acc[mt][nt][i];
        }
  } else {
    const bool isQ = (n0 < 2048);
    const float scale = isQ ? SCALE_LOG2 : 1.0f;
    __bf16* dst = isQ ? Qb : Kb;
    const int ldd = isQ ? 2048 : 512;
    const int noff = isQ ? 0 : 2048;
    const bool odd = lid & 1;
#pragma unroll
    for (int nt = 0; nt < 4; nt++) {
      int nn = n0 + wn + nt * 16 + lid;
      int fi = (nn & 63) >> 1;
      float inv = __builtin_amdgcn_exp2f(-(float)fi * L2_10K_32);
#pragma unroll
      for (int mt = 0; mt < 2; mt++)
#pragma unroll
        for (int i = 0; i < 4; i++) {
          int mm = m0 + wm + mt * 16 + quad * 4 + i;
          float ang = (float)mm * inv;
          float sn, cs;
          __sincosf(ang, &sn, &cs);
          float v = acc[mt][nt][i];
          float p = __shfl_xor(v, 1);
          float o = v * cs + (odd ? p : -p) * sn;
          dst[(size_t)mm * ldd + nn - noff] = (__bf16)(o * scale);
        }
    }
  }
}

// ---------------------------------------------------------------- out GEMM
__global__ __launch_bounds__(256) void k_gemm_out(
    const __bf16* __restrict__ A, const __bf16* __restrict__ Bt,
    float* __restrict__ C) {
  const int K = 2048, N = 2048;
  __shared__ __bf16 As[64][64];
  __shared__ __bf16 Bs[128][64];
  const int tid = threadIdx.x;
  const int m0 = blockIdx.x * 64, n0 = blockIdx.y * 128;
  const int w = tid >> 6, lane = tid & 63, quad = lane >> 4, lid = lane & 15;
  const int wm = (w & 1) * 32, wn = (w >> 1) * 64;
  const int r0 = tid >> 3;
  const int cg0 = (((tid & 7) ^ (r0 & 7)) * 8);
  const __bf16* Ag = A + (size_t)(m0 + r0) * K + cg0;
  const __bf16* Bg = Bt + (size_t)(n0 + r0) * K + cg0;
  __bf16* Asl = &As[0][0] + tid * 8;
  __bf16* Bsl = &Bs[0][0] + tid * 8;
  const int cl = ((quad ^ (lid & 7)) * 8);
  f32x4 acc[2][4] = {};
  for (int k0 = 0; k0 < K; k0 += 64) {
    __syncthreads();
    glds16(Ag + k0, Asl);
    glds16(Ag + (size_t)32 * K + k0, Asl + 2048);
    glds16(Bg + k0, Bsl);
    glds16(Bg + (size_t)32 * K + k0, Bsl + 2048);
    glds16(Bg + (size_t)64 * K + k0, Bsl + 4096);
    glds16(Bg + (size_t)96 * K + k0, Bsl + 6144);
    __syncthreads();
    bf16x8 a[2][2], b[4][2];
#pragma unroll
    for (int mt = 0; mt < 2; mt++) {
      a[mt][0] = *(const bf16x8*)(&As[wm + mt * 16 + lid][cl]);
      a[mt][1] = *(const bf16x8*)(&As[wm + mt * 16 + lid][cl ^ 32]);
    }
#pragma unroll
    for (int nt = 0; nt < 4; nt++) {
      b[nt][0] = *(const bf16x8*)(&Bs[wn + nt * 16 + lid][cl]);
      b[nt][1] = *(const bf16x8*)(&Bs[wn + nt * 16 + lid][cl ^ 32]);
    }
#pragma unroll
    for (int mt = 0; mt < 2; mt++)
#pragma unroll
      for (int nt = 0; nt < 4; nt++) {
        acc[mt][nt] = __builtin_amdgcn_mfma_f32_16x16x32_bf16(
            a[mt][0], b[nt][0], acc[mt][nt], 0, 0, 0);
        acc[mt][nt] = __builtin_amdgcn_mfma_f32_16x16x32_bf16(
            a[mt][1], b[nt][1], acc[mt][nt], 0, 0, 0);
      }
  }
#pragma unroll
  for (int mt = 0; mt < 2; mt++)
#pragma unroll
    for (int nt = 0; nt < 4; nt++)
#pragma unroll
      for (int i = 0; i < 4; i++) {
        int mm = m0 + wm + mt * 16 + quad * 4 + i;
        int nn = n0 + wn + nt * 16 + lid;
        C[(size_t)mm * N + nn] = acc[mt][nt][i];
      }
}

// ---------------------------------------------------------------- attention
// Block = (head, 64-q tile), 4 waves: qh=w&1, kh=w>>1 (kv-split).
// Max-free softmax (exp2 domain, Q pre-scaled). K/V staged via glds into
// DOUBLE-BUFFERED LDS: prefetch kt+1 issues before compute of kt; one
// barrier/iter at loop end (drain overlaps compute). Epilogue merge buffer
// aliases the dead K/V LDS.
__global__ __launch_bounds__(256, 3) void k_attn(
    const __bf16* __restrict__ Q, const __bf16* __restrict__ Kc,
    const __bf16* __restrict__ Vt, __bf16* __restrict__ Oc) {
  __shared__ char smem[43008];
  __bf16* KsB = (__bf16*)smem;             // [2][64][64] rows=kv
  __bf16* VsB = (__bf16*)(smem + 16384);   // [2][64][64] rows=hd
  __bf16* PsB = (__bf16*)(smem + 32768);   // [4][32][40] per-wave P
  float*  OL  = (float*)smem;              // epilogue: [2][32][68] (aliases Ks)
  float*  Lsh = (float*)(smem + 17408);    // epilogue: [64] (aliases Vs)
  const int h = blockIdx.x;
  const int qt = 31 - blockIdx.y;          // longest blocks first
  const int q0 = qt * 64;
  const int kvh = h >> 2;
  const int tid = threadIdx.x;
  const int w = tid >> 6, lane = tid & 63, quad = lane >> 4, lid = lane & 15;
  const int qh = w & 1, kh = w >> 1;
  const int r0 = tid >> 3;
  const int cg0 = (((tid & 7) ^ (r0 & 7)) * 8);

  // Q A-fragments direct from global
  bf16x8 aq[2][2];
#pragma unroll
  for (int mt = 0; mt < 2; mt++)
#pragma unroll
    for (int ks = 0; ks < 2; ks++)
      aq[mt][ks] = *(const bf16x8*)(
          Q + (size_t)(q0 + qh * 32 + mt * 16 + lid) * 2048 + h * 64 +
          ks * 32 + quad * 8);

  bf16x8 bone;
#pragma unroll
  for (int j = 0; j < 8; j++) bone[j] = (lid == 0) ? (__bf16)1.0f : (__bf16)0.0f;

  const __bf16* Kg = Kc + kvh * 64 + cg0;
  const __bf16* Vg = Vt + ((size_t)(kvh * 64 + r0)) * 2048 + cg0;
  __bf16* Pw = PsB + w * 1280;

  // prologue: stage K/V tile 0 into buffer 0
  glds16(Kg + (size_t)r0 * 512,        KsB + tid * 8);
  glds16(Kg + (size_t)(r0 + 32) * 512, KsB + (tid + 256) * 8);
  glds16(Vg,                           VsB + tid * 8);
  glds16(Vg + (size_t)32 * 2048,       VsB + (tid + 256) * 8);
  __syncthreads();

  f32x4 Oacc[2][4] = {};
  f32x4 Lacc[2] = {};

  for (int kt = 0; kt <= qt; kt++) {
    const int cb = kt & 1;
    if (kt < qt) {                         // prefetch kt+1 into other buffer
      const int nb = cb ^ 1;
      const size_t kv1 = (size_t)(kt + 1) * 64;
      glds16(Kg + (kv1 + r0) * 512,        KsB + nb * 4096 + tid * 8);
      glds16(Kg + (kv1 + r0 + 32) * 512,   KsB + nb * 4096 + (tid + 256) * 8);
      glds16(Vg + kv1,                     VsB + nb * 4096 + tid * 8);
      glds16(Vg + (size_t)32 * 2048 + kv1, VsB + nb * 4096 + (tid + 256) * 8);
    }

    // S = Q K^T for this wave's 32q x 32kv quadrant (exp2 domain)
    f32x4 Sc[2][2] = {};
#pragma unroll
    for (int nt = 0; nt < 2; nt++) {
      int krow = kh * 32 + nt * 16 + lid;
      int cl = (quad ^ (lid & 7)) * 8;
      bf16x8 b0 = *(const bf16x8*)(KsB + cb * 4096 + krow * 64 + cl);
      bf16x8 b1 = *(const bf16x8*)(KsB + cb * 4096 + krow * 64 + (cl ^ 32));
#pragma unroll
      for (int mt = 0; mt < 2; mt++) {
        Sc[mt][nt] = __builtin_amdgcn_mfma_f32_16x16x32_bf16(aq[mt][0], b0, Sc[mt][nt], 0, 0, 0);
        Sc[mt][nt] = __builtin_amdgcn_mfma_f32_16x16x32_bf16(aq[mt][1], b1, Sc[mt][nt], 0, 0, 0);
      }
    }
    if (kt == qt) {                        // causal mask on diagonal tile
#pragma unroll
      for (int mt = 0; mt < 2; mt++)
#pragma unroll
        for (int nt = 0; nt < 2; nt++)
#pragma unroll
          for (int i = 0; i < 4; i++) {
            int kvg = kt * 64 + kh * 32 + nt * 16 + lid;
            int qrg = q0 + qh * 32 + mt * 16 + quad * 4 + i;
            if (kvg > qrg) Sc[mt][nt][i] = -1e30f;
          }
    }

    // P = exp2(S), pair-pack -> Ps (wave-private, in-wave DS ordering)
#pragma unroll
    for (int mt = 0; mt < 2; mt++)
#pragma unroll
      for (int i = 0; i < 4; i++) {
        float pA = __builtin_amdgcn_exp2f(Sc[mt][0][i]);
        float pB = __builtin_amdgcn_exp2f(Sc[mt][1][i]);
        float send = (lid & 1) ? pA : pB;
        float recv = pair_swap(send);
        float lo = (lid & 1) ? recv : pA;
        float hi = (lid & 1) ? pB : recv;
        int row = mt * 16 + quad * 4 + i;
        int col = (lid & 1) ? (lid + 15) : lid;
        *(unsigned*)(Pw + row * 40 + col) = pack_bf16(lo, hi);
      }

    // O += P V ; L += P @ ones
    bf16x8 ap[2];
#pragma unroll
    for (int mt = 0; mt < 2; mt++)
      ap[mt] = *(const bf16x8*)(Pw + (mt * 16 + lid) * 40 + quad * 8);
#pragma unroll
    for (int mt = 0; mt < 2; mt++)
      Lacc[mt] = __builtin_amdgcn_mfma_f32_16x16x32_bf16(ap[mt], bone, Lacc[mt], 0, 0, 0);
#pragma unroll
    for (int nt = 0; nt < 4; nt++) {
      bf16x8 bv = *(const bf16x8*)(
          VsB + cb * 4096 + (nt * 16 + lid) * 64 + (((kh * 4 + quad) ^ (lid & 7)) * 8));
#pragma unroll
      for (int mt = 0; mt < 2; mt++)
        Oacc[mt][nt] = __builtin_amdgcn_mfma_f32_16x16x32_bf16(ap[mt], bv, Oacc[mt][nt], 0, 0, 0);
    }
    __syncthreads();                       // drains prefetch; protects buffers
  }

  // merge kv-halves (OL/Lsh alias dead K/V buffers; loop-end barrier covers)
  if (kh == 1) {
#pragma unroll
    for (int mt = 0; mt < 2; mt++)
#pragma unroll
      for (int nt = 0; nt < 4; nt++)
#pragma unroll
        for (int i = 0; i < 4; i++)
          OL[qh * 2176 + (mt * 16 + quad * 4 + i) * 68 + nt * 16 + lid] =
              Oacc[mt][nt][i];
    if (lid == 0)
#pragma unroll
      for (int mt = 0; mt < 2; mt++)
#pragma unroll
        for (int i = 0; i < 4; i++)
          Lsh[qh * 32 + mt * 16 + quad * 4 + i] = Lacc[mt][i];
  }
  __syncthreads();
  if (kh == 0) {
#pragma unroll
    for (int mt = 0; mt < 2; mt++)
#pragma unroll
      for (int i = 0; i < 4; i++) {
        int row = mt * 16 + quad * 4 + i;
        float lsum = __shfl(Lacc[mt][i], lane & 48) + Lsh[qh * 32 + row];
        float rs = 1.0f / lsum;
#pragma unroll
        for (int nt = 0; nt < 4; nt++) {
          float o = Oacc[mt][nt][i] + OL[qh * 2176 + row * 68 + nt * 16 + lid];
          Oc[(size_t)(q0 + qh * 32 + row) * 2048 + h * 64 + nt * 16 + lid] =
              (__bf16)(o * rs);
        }
      }
  }
}

// ---------------------------------------------------------------- launch
extern "C" void kernel_launch(void* const* d_in, const int* in_sizes, int n_in,
                              void* d_out, int out_size, void* d_ws, size_t ws_size,
                              hipStream_t stream) {
  const float* hx = (const float*)d_in[0];
  const float* Wq = (const float*)d_in[1];
  const float* Wk = (const float*)d_in[2];
  const float* Wv = (const float*)d_in[3];
  const float* Wo = (const float*)d_in[4];
  float* out = (float*)d_out;

  char* ws = (char*)d_ws;
  size_t off = 0;
  auto alloc = [&](size_t bytes) -> void* {
    void* p = ws + off;
    off += (bytes + 255) & ~(size_t)255;
    return p;
  };
  __bf16* Xb    = (__bf16*)alloc((size_t)2048 * 2048 * 2);
  __bf16* Wqkvt = (__bf16*)alloc((size_t)3072 * 2048 * 2);
  __bf16* Wot   = (__bf16*)alloc((size_t)2048 * 2048 * 2);
  __bf16* Qb    = (__bf16*)alloc((size_t)2048 * 2048 * 2);
  __bf16* Kb    = (__bf16*)alloc((size_t)2048 * 512 * 2);
  __bf16* Vb    = (__bf16*)alloc((size_t)2048 * 512 * 2);
  __bf16* Vtg   = (__bf16*)alloc((size_t)512 * 2048 * 2);
  __bf16* AOb   = (__bf16*)alloc((size_t)2048 * 2048 * 2);

  // 1. prep: x->bf16 + weight transposes
  k_prep<<<dim3(224, 64), 256, 0, stream>>>(hx, Wq, Wk, Wv, Wo, Xb, Wqkvt, Wot);
  // 2. fused QKV GEMM (BK=64) with RoPE epilogue
  k_gemm_qkv<<<dim3(32, 24), 256, 0, stream>>>(Xb, Wqkvt, Qb, Kb, Vb);
  // 3. V transpose
  k_vtrans_b<<<dim3(16, 64), dim3(32, 8), 0, stream>>>(Vb, Vtg);
  // 4. causal GQA flash attention (dbuf + kv-split + max-free)
  k_attn<<<dim3(NH, 32), 256, 0, stream>>>(Qb, Kb, Vtg, AOb);
  // 5. out proj (BK=64) -> fp32 d_out
  k_gemm_out<<<dim3(32, 16), 256, 0, stream>>>(AOb, Wot, out);
}